// Round 1
// baseline (105.466 us; speedup 1.0000x reference)
//
#include <hip/hip_runtime.h>
#include <math.h>

// WavefunctionEmbedding, fully fused single kernel (NO workspace):
//   out[b,i,2k+0/1] = sum_j amp_ij * {cos,sin}(wn_k * r_ij)
// Block owns ROWS=4 rows: radial histograms in LDS (cubic Lagrange deposit,
// int32 fixed-point ds_add), then in-block contraction against
// cos/sin(wn_k * r_q) via per-thread Chebyshev recurrence.
//
// R13 = R12 with the contraction restructured to CPT=4 column-pairs per
// thread (wave = q-team). Rationale: contraction was LDS-return-BW bound --
// total broadcast ds_read_b128 count = rows*groups*4/CPT, independent of
// block shape; only CPT shrinks it. CPT 1->4 cuts per-CU broadcast reads
// 3168 -> ~780 (25K -> 6.2K LDS cycles), making the phase VALU-bound.
//   - NTHREADS 512 -> 256 (4 waves): keeps 3 blocks/CU at the bigger
//     register state (acc 4x4 f32x2 + 4x Chebyshev track = ~56 persistent
//     VGPRs; 3 waves/SIMD allows up to 170).
//   - team merge: zero-init msum + ds_add_f32 LDS atomics (8 KB), replaces
//     the old f32x2 merge buffer. 2-way bank aliasing only (free).
// Histogram phase bit-identical to R12; only partial-sum order changes
// (2 -> 4 q-partials, float-atomic merge) -> absmax expected ~0.03125.
// (R11's readlane experiment regressed: readlane is a VALU op per value, so
// it REPLACED the LDS broadcasts with VALU ops on the busy pipe. CPT
// amortization shrinks the broadcast count itself instead.)

#define N_FIXED  1536
#define K_FIXED  256
#define QBINS    256
#define QG       260            // node q represents r = (q-1)*h
#define ROWS     4              // rows per block (768 blocks = 3/CU)
#define RSTRIDE  272            // hist row stride in floats (16B-aligned)
#define NTHREADS 256
#define NWAVES   (NTHREADS / 64)
#define CPT      4              // column-pairs per thread
#define FPSCALE  4194304.0f     // 2^22 fixed-point scale for hist deposits

typedef __attribute__((ext_vector_type(2))) float f32x2;

// ---------------- fallback: direct kernel (round-1, known-good) ------------
__global__ __launch_bounds__(256) void wf_direct_kernel(
    const float* __restrict__ coords, const unsigned char* __restrict__ mask,
    const float* __restrict__ wavenumbers, float* __restrict__ out, int N, int K)
{
    __shared__ float2 pairs[N_FIXED];
    const int row = blockIdx.x;
    const int b   = row / N;
    const int i   = row - b * N;
    const int t   = threadIdx.x;
    const float* crow = coords + (size_t)b * N * 3;
    const float xi = crow[i*3+0], yi = crow[i*3+1], zi = crow[i*3+2];
    const unsigned char* mrow = mask + (size_t)b * N;
    for (int j = t; j < N; j += blockDim.x) {
        float dx = crow[j*3+0]-xi, dy = crow[j*3+1]-yi, dz = crow[j*3+2]-zi;
        float d2 = fmaf(dx,dx, fmaf(dy,dy, fmaf(dz,dz, 1e-12f)));
        float r  = sqrtf(d2);
        float amp = 0.07957747154594767f / fmaxf(r, 1e-6f);
        if (j == i || mrow[j]) amp = 0.0f;
        pairs[j] = make_float2(r, amp);
    }
    __syncthreads();
    const int k = t;
    const float f = wavenumbers[k] * 0.15915494309189535f;
    float re = 0.0f, im = 0.0f;
    #pragma unroll 4
    for (int j = 0; j < N; ++j) {
        float2 p = pairs[j];
        float x  = __builtin_amdgcn_fractf(p.x * f);
        float c  = __builtin_amdgcn_cosf(x);
        float s  = __builtin_amdgcn_sinf(x);
        re = fmaf(c, p.y, re);
        im = fmaf(s, p.y, im);
    }
    float2* orow = (float2*)out + (size_t)row * K;
    orow[k] = make_float2(re, im);
}

// ---------------- fused: hist + CPT=4 packed in-block contraction ----------
__global__ __launch_bounds__(NTHREADS) void wf_fused_kernel(
    const float* __restrict__ coords, const unsigned char* __restrict__ mask,
    const float* __restrict__ wavenumbers, float* __restrict__ out, int N)
{
    __shared__ int   hist[ROWS * RSTRIDE];         // 4.25 KB, r-major
    __shared__ float red[NWAVES];
    __shared__ f32x2 msum[ROWS * K_FIXED];         // 8 KB float-atomic merge

    const int i0 = blockIdx.x * ROWS;      // first global row of this block
    const int b  = i0 / N;                 // N % ROWS == 0 -> block within b
    const int t  = threadIdx.x;

    const float* crow = coords + (size_t)b * N * 3;
    const unsigned char* mrow = mask + (size_t)b * N;

    // ---- rmax over THIS BATCH only (h is per-block-consistent) ----
    float m = 0.0f;
    #pragma unroll
    for (int s = 0; s < N_FIXED / NTHREADS; ++s) {
        const int p = t + NTHREADS * s;
        float x = crow[3*p], y = crow[3*p+1], z = crow[3*p+2];
        m = fmaxf(m, fmaf(x,x, fmaf(y,y, z*z)));
    }
    #pragma unroll
    for (int off = 32; off >= 1; off >>= 1)
        m = fmaxf(m, __shfl_down(m, off, 64));
    if ((t & 63) == 0) red[t >> 6] = m;
    for (int a = t; a < ROWS * RSTRIDE; a += NTHREADS) hist[a] = 0;
    {
        float* mz = (float*)msum;
        for (int a = t; a < ROWS * K_FIXED * 2; a += NTHREADS) mz[a] = 0.0f;
    }
    __syncthreads();
    float mm = red[0];
    #pragma unroll
    for (int w = 1; w < NWAVES; ++w) mm = fmaxf(mm, red[w]);
    const float rmax = 2.0005f * sqrtf(mm) + 1e-3f;   // r_ij <= 2 max|c|
    const float h    = rmax / (float)QBINS;           // => u = r/h < 256
    const float inv_h = 1.0f / h;

    // ---- histograms: each j loaded once, deposit into all ROWS rows ----
    const int il0 = i0 - b * N;            // local i of row 0
    float cx[ROWS], cy[ROWS], cz[ROWS];
    #pragma unroll
    for (int r = 0; r < ROWS; ++r) {
        cx[r] = crow[3*(il0+r)];
        cy[r] = crow[3*(il0+r)+1];
        cz[r] = crow[3*(il0+r)+2];
    }

    #pragma unroll
    for (int s = 0; s < N_FIXED / NTHREADS; ++s) {
        const int j = t + NTHREADS * s;
        const float xj = crow[3*j], yj = crow[3*j+1], zj = crow[3*j+2];
        const bool masked = (mrow[j] != 0);
        #pragma unroll
        for (int r = 0; r < ROWS; ++r) {
            float dx = xj - cx[r];
            float dy = yj - cy[r];
            float dz = zj - cz[r];
            float d2 = fmaf(dx,dx, fmaf(dy,dy, fmaf(dz,dz, 1e-12f)));
            float rsq = __builtin_amdgcn_rsqf(d2);     // 1/r, r >= 1e-6
            float amp = 0.07957747154594767f * rsq;    // 1/(4 pi r)
            if (j == il0 + r || masked) amp = 0.0f;

            float u  = d2 * rsq * inv_h;               // r/h, in [0,256)
            float qf = floorf(u);
            int   q0 = (int)qf;                        // 0..255, no clamp
            float tt = u - qf;
            // Lagrange cubic through nodes {-1,0,1,2} at offset tt in [0,1)
            float as6 = amp * (FPSCALE * (1.0f/6.0f));
            float as2 = amp * (FPSCALE * 0.5f);
            float tm1 = tt + 1.0f, t1 = tt - 1.0f, t2 = tt - 2.0f;
            float p  = tt  * t1;                       // t(t-1)
            float qq = tm1 * t2;                       // (t+1)(t-2)
            int w0 = (int)(-(p  * t2)  * as6);         // truncating cvt
            int w1 = (int)( (qq * t1)  * as2);
            int w2 = (int)(-(qq * tt)  * as2);
            int w3 = (int)( (p  * tm1) * as6);
            int* hb = &hist[r * RSTRIDE + q0];
            atomicAdd(hb + 0, w0);                     // native ds_add
            atomicAdd(hb + 1, w1);
            atomicAdd(hb + 2, w2);
            atomicAdd(hb + 3, w3);
        }
    }
    __syncthreads();

    // ---- convert int -> float in place (each slot one thread) ----
    float* hf = (float*)hist;
    const float invS = 1.0f / FPSCALE;
    for (int a = t; a < ROWS * RSTRIDE; a += NTHREADS)
        hf[a] = (float)hist[a] * invS;
    __syncthreads();

    // ---- contraction: team = wave owns a q-range; thread owns CPT=4
    //      column-pairs (c0, c0+64, c0+128, c0+192) for all 4 rows ----
    const int wv   = t >> 6;               // wave/team 0..3
    const int c0   = t & 63;
    const int gbeg = (wv == 0) ? 0 : (16 * wv + 1);   // 65 groups: 17/16/16/16
    const int gend = 16 * wv + 17;
    const int qs   = gbeg * 4;

    // theta (revolutions per node) = wn_c * h / 2pi; per-column Chebyshev
    f32x2 k2[CPT], wa[CPT], wb[CPT];
    #pragma unroll
    for (int cc = 0; cc < CPT; ++cc) {
        const float xr  = wavenumbers[c0 + 64 * cc] * 0.15915494309189535f * h;
        const float k2s = 2.0f * __builtin_amdgcn_cosf(__builtin_amdgcn_fractf(xr));
        k2[cc] = (f32x2){k2s, k2s};
        // seeds: w_a = cis((qs-1)*th), w_b = cis(qs*th); both (cos,sin)
        const float aarg = __builtin_amdgcn_fractf((float)(qs - 1) * xr);
        const float barg = __builtin_amdgcn_fractf((float)qs * xr);
        wa[cc] = (f32x2){__builtin_amdgcn_cosf(aarg), __builtin_amdgcn_sinf(aarg)};
        wb[cc] = (f32x2){__builtin_amdgcn_cosf(barg), __builtin_amdgcn_sinf(barg)};
    }

    f32x2 acc[CPT][ROWS];
    #pragma unroll
    for (int cc = 0; cc < CPT; ++cc)
        #pragma unroll
        for (int r = 0; r < ROWS; ++r) acc[cc][r] = (f32x2){0.0f, 0.0f};

    #pragma unroll 2
    for (int g = gbeg; g < gend; ++g) {
        const int q0 = g * 4;
        const float4 h0 = *(const float4*)&hf[0 * RSTRIDE + q0]; // ds_read_b128
        const float4 h1 = *(const float4*)&hf[1 * RSTRIDE + q0];
        const float4 h2 = *(const float4*)&hf[2 * RSTRIDE + q0];
        const float4 h3 = *(const float4*)&hf[3 * RSTRIDE + q0];
        const float r0[4] = {h0.x, h0.y, h0.z, h0.w};
        const float r1[4] = {h1.x, h1.y, h1.z, h1.w};
        const float r2[4] = {h2.x, h2.y, h2.z, h2.w};
        const float r3[4] = {h3.x, h3.y, h3.z, h3.w};
        #pragma unroll
        for (int d = 0; d < 4; ++d) {
            const f32x2 s0 = {r0[d], r0[d]};
            const f32x2 s1 = {r1[d], r1[d]};
            const f32x2 s2 = {r2[d], r2[d]};
            const f32x2 s3 = {r3[d], r3[d]};
            #pragma unroll
            for (int cc = 0; cc < CPT; ++cc) {
                // packed acc: v_pk_fma_f32 (splat h, multiply (cos,sin))
                acc[cc][0] = __builtin_elementwise_fma(s0, wa[cc], acc[cc][0]);
                acc[cc][1] = __builtin_elementwise_fma(s1, wa[cc], acc[cc][1]);
                acc[cc][2] = __builtin_elementwise_fma(s2, wa[cc], acc[cc][2]);
                acc[cc][3] = __builtin_elementwise_fma(s3, wa[cc], acc[cc][3]);
                // packed Chebyshev step: w_{q+1} = k2*w_q - w_{q-1}
                const f32x2 wn = __builtin_elementwise_fma(k2[cc], wb[cc], -wa[cc]);
                wa[cc] = wb[cc]; wb[cc] = wn;
            }
        }
    }

    // ---- merge the 4 q-team partials via LDS float atomics, store ----
    float* msumf = (float*)msum;
    #pragma unroll
    for (int cc = 0; cc < CPT; ++cc) {
        const int col = c0 + 64 * cc;
        #pragma unroll
        for (int r = 0; r < ROWS; ++r) {
            atomicAdd(&msumf[(r * K_FIXED + col) * 2 + 0], acc[cc][r].x);  // ds_add_f32
            atomicAdd(&msumf[(r * K_FIXED + col) * 2 + 1], acc[cc][r].y);
        }
    }
    __syncthreads();

    for (int idx = t; idx < ROWS * K_FIXED; idx += NTHREADS) {
        const f32x2 v = msum[idx];
        ((float2*)out)[(size_t)(i0 + (idx >> 8)) * K_FIXED + (idx & 255)] =
            make_float2(v.x, v.y);
    }
}

extern "C" void kernel_launch(void* const* d_in, const int* in_sizes, int n_in,
                              void* d_out, int out_size, void* d_ws, size_t ws_size,
                              hipStream_t stream) {
    const float* coords          = (const float*)d_in[0];
    const unsigned char* mask    = (const unsigned char*)d_in[1];
    const float* wavenumbers     = (const float*)d_in[2];
    float* out                   = (float*)d_out;

    const int K  = in_sizes[2];
    const int BN = in_sizes[0] / 3;        // B*N
    const int N  = N_FIXED;

    if (K != K_FIXED || BN % N != 0 || (N % ROWS) != 0 ||
        (N % NTHREADS) != 0) {
        wf_direct_kernel<<<BN, K, 0, stream>>>(coords, mask, wavenumbers, out, N, K);
        return;
    }

    wf_fused_kernel<<<BN / ROWS, NTHREADS, 0, stream>>>(coords, mask,
                                                        wavenumbers, out, N);
}

// Round 2
// 104.468 us; speedup vs baseline: 1.0096x; 1.0096x over previous
//
#include <hip/hip_runtime.h>
#include <math.h>

// WavefunctionEmbedding, fully fused single kernel (NO workspace):
//   out[b,i,2k+0/1] = sum_j amp_ij * {cos,sin}(wn_k * r_ij)
// Block owns ROWS=4 rows: radial histograms in LDS (cubic Lagrange deposit,
// int32 fixed-point ds_add), then in-block contraction against
// cos/sin(wn_k * r_q) via per-thread Chebyshev recurrence.
//
// R14 = R12 structure (512 thr, 8 waves, 3 blocks/CU) + CPT=2 contraction.
// R13 post-mortem: CPT=4 @ 256 thr regressed 19->52 us because the f32x2
// ARRAY state (acc[4][4], wa/wb/k2[4]) was demoted to scratch (VGPR_Count=48
// vs ~72 needed -> every FMA round-tripped scratch), and 4 waves/block halved
// latency hiding for the deposit atomics. Fixes here:
//   - CPT=2 only: 4 q-teams x 128 threads; thread owns cols c and c+128.
//     Per-block broadcast ds_read_b128: 1056 -> 520 (the LDS-return-BW
//     invariant reads = rows*groups*4/CPT; only CPT shrinks it).
//   - ALL contraction state in NAMED scalars (a00..a13, wa0/wb0/k20,
//     wa1/wb1/k21) so the compiler cannot demote to scratch (rule #20).
//   - NTHREADS back to 512: deposit phase bit-identical to R12.
// Team merge: zero-init msum + ds_add_f32 (validated in R13, absmax 0.03125).

#define N_FIXED  1536
#define K_FIXED  256
#define QBINS    256
#define QG       260            // node q represents r = (q-1)*h
#define ROWS     4              // rows per block (768 blocks = 3/CU)
#define RSTRIDE  272            // hist row stride in floats (16B-aligned)
#define NTHREADS 512
#define NWAVES   (NTHREADS / 64)
#define FPSCALE  4194304.0f     // 2^22 fixed-point scale for hist deposits

typedef __attribute__((ext_vector_type(2))) float f32x2;

// ---------------- fallback: direct kernel (round-1, known-good) ------------
__global__ __launch_bounds__(256) void wf_direct_kernel(
    const float* __restrict__ coords, const unsigned char* __restrict__ mask,
    const float* __restrict__ wavenumbers, float* __restrict__ out, int N, int K)
{
    __shared__ float2 pairs[N_FIXED];
    const int row = blockIdx.x;
    const int b   = row / N;
    const int i   = row - b * N;
    const int t   = threadIdx.x;
    const float* crow = coords + (size_t)b * N * 3;
    const float xi = crow[i*3+0], yi = crow[i*3+1], zi = crow[i*3+2];
    const unsigned char* mrow = mask + (size_t)b * N;
    for (int j = t; j < N; j += blockDim.x) {
        float dx = crow[j*3+0]-xi, dy = crow[j*3+1]-yi, dz = crow[j*3+2]-zi;
        float d2 = fmaf(dx,dx, fmaf(dy,dy, fmaf(dz,dz, 1e-12f)));
        float r  = sqrtf(d2);
        float amp = 0.07957747154594767f / fmaxf(r, 1e-6f);
        if (j == i || mrow[j]) amp = 0.0f;
        pairs[j] = make_float2(r, amp);
    }
    __syncthreads();
    const int k = t;
    const float f = wavenumbers[k] * 0.15915494309189535f;
    float re = 0.0f, im = 0.0f;
    #pragma unroll 4
    for (int j = 0; j < N; ++j) {
        float2 p = pairs[j];
        float x  = __builtin_amdgcn_fractf(p.x * f);
        float c  = __builtin_amdgcn_cosf(x);
        float s  = __builtin_amdgcn_sinf(x);
        re = fmaf(c, p.y, re);
        im = fmaf(s, p.y, im);
    }
    float2* orow = (float2*)out + (size_t)row * K;
    orow[k] = make_float2(re, im);
}

// ---------------- fused: hist + CPT=2 packed in-block contraction ----------
__global__ __launch_bounds__(NTHREADS) void wf_fused_kernel(
    const float* __restrict__ coords, const unsigned char* __restrict__ mask,
    const float* __restrict__ wavenumbers, float* __restrict__ out, int N)
{
    __shared__ int   hist[ROWS * RSTRIDE];         // 4.25 KB, r-major
    __shared__ float red[NWAVES];
    __shared__ f32x2 msum[ROWS * K_FIXED];         // 8 KB float-atomic merge

    const int i0 = blockIdx.x * ROWS;      // first global row of this block
    const int b  = i0 / N;                 // N % ROWS == 0 -> block within b
    const int t  = threadIdx.x;

    const float* crow = coords + (size_t)b * N * 3;
    const unsigned char* mrow = mask + (size_t)b * N;

    // ---- rmax over THIS BATCH only (h is per-block-consistent) ----
    float m = 0.0f;
    #pragma unroll
    for (int s = 0; s < N_FIXED / NTHREADS; ++s) {
        const int p = t + NTHREADS * s;
        float x = crow[3*p], y = crow[3*p+1], z = crow[3*p+2];
        m = fmaxf(m, fmaf(x,x, fmaf(y,y, z*z)));
    }
    #pragma unroll
    for (int off = 32; off >= 1; off >>= 1)
        m = fmaxf(m, __shfl_down(m, off, 64));
    if ((t & 63) == 0) red[t >> 6] = m;
    for (int a = t; a < ROWS * RSTRIDE; a += NTHREADS) hist[a] = 0;
    {
        float* mz = (float*)msum;
        for (int a = t; a < ROWS * K_FIXED * 2; a += NTHREADS) mz[a] = 0.0f;
    }
    __syncthreads();
    float mm = red[0];
    #pragma unroll
    for (int w = 1; w < NWAVES; ++w) mm = fmaxf(mm, red[w]);
    const float rmax = 2.0005f * sqrtf(mm) + 1e-3f;   // r_ij <= 2 max|c|
    const float h    = rmax / (float)QBINS;           // => u = r/h < 256
    const float inv_h = 1.0f / h;

    // ---- histograms: each j loaded once, deposit into all ROWS rows ----
    const int il0 = i0 - b * N;            // local i of row 0
    float cx[ROWS], cy[ROWS], cz[ROWS];
    #pragma unroll
    for (int r = 0; r < ROWS; ++r) {
        cx[r] = crow[3*(il0+r)];
        cy[r] = crow[3*(il0+r)+1];
        cz[r] = crow[3*(il0+r)+2];
    }

    #pragma unroll
    for (int s = 0; s < N_FIXED / NTHREADS; ++s) {
        const int j = t + NTHREADS * s;
        const float xj = crow[3*j], yj = crow[3*j+1], zj = crow[3*j+2];
        const bool masked = (mrow[j] != 0);
        #pragma unroll
        for (int r = 0; r < ROWS; ++r) {
            float dx = xj - cx[r];
            float dy = yj - cy[r];
            float dz = zj - cz[r];
            float d2 = fmaf(dx,dx, fmaf(dy,dy, fmaf(dz,dz, 1e-12f)));
            float rsq = __builtin_amdgcn_rsqf(d2);     // 1/r, r >= 1e-6
            float amp = 0.07957747154594767f * rsq;    // 1/(4 pi r)
            if (j == il0 + r || masked) amp = 0.0f;

            float u  = d2 * rsq * inv_h;               // r/h, in [0,256)
            float qf = floorf(u);
            int   q0 = (int)qf;                        // 0..255, no clamp
            float tt = u - qf;
            // Lagrange cubic through nodes {-1,0,1,2} at offset tt in [0,1)
            float as6 = amp * (FPSCALE * (1.0f/6.0f));
            float as2 = amp * (FPSCALE * 0.5f);
            float tm1 = tt + 1.0f, t1 = tt - 1.0f, t2 = tt - 2.0f;
            float p  = tt  * t1;                       // t(t-1)
            float qq = tm1 * t2;                       // (t+1)(t-2)
            int w0 = (int)(-(p  * t2)  * as6);         // truncating cvt
            int w1 = (int)( (qq * t1)  * as2);
            int w2 = (int)(-(qq * tt)  * as2);
            int w3 = (int)( (p  * tm1) * as6);
            int* hb = &hist[r * RSTRIDE + q0];
            atomicAdd(hb + 0, w0);                     // native ds_add
            atomicAdd(hb + 1, w1);
            atomicAdd(hb + 2, w2);
            atomicAdd(hb + 3, w3);
        }
    }
    __syncthreads();

    // ---- convert int -> float in place (each slot one thread) ----
    float* hf = (float*)hist;
    const float invS = 1.0f / FPSCALE;
    for (int a = t; a < ROWS * RSTRIDE; a += NTHREADS)
        hf[a] = (float)hist[a] * invS;
    __syncthreads();

    // ---- contraction: 4 q-teams x 128 threads; thread owns cols c, c+128
    //      for all 4 rows. All state in NAMED registers (no arrays). ----
    const int team = t >> 7;               // 0..3
    const int c    = t & 127;
    const int gbeg = (team == 0) ? 0 : (16 * team + 1);  // 65 groups: 17/16/16/16
    const int gend = 16 * team + 17;
    const int qs   = gbeg * 4;

    // theta (revolutions per node) = wn * h / 2pi; per-column Chebyshev
    const float xr0 = wavenumbers[c]       * 0.15915494309189535f * h;
    const float xr1 = wavenumbers[c + 128] * 0.15915494309189535f * h;
    const float k2s0 = 2.0f * __builtin_amdgcn_cosf(__builtin_amdgcn_fractf(xr0));
    const float k2s1 = 2.0f * __builtin_amdgcn_cosf(__builtin_amdgcn_fractf(xr1));
    const f32x2 k20 = {k2s0, k2s0};
    const f32x2 k21 = {k2s1, k2s1};
    // Chebyshev seeds: w_a = cis((qs-1)*th), w_b = cis(qs*th); (cos,sin)
    const float a0arg = __builtin_amdgcn_fractf((float)(qs - 1) * xr0);
    const float b0arg = __builtin_amdgcn_fractf((float)qs * xr0);
    const float a1arg = __builtin_amdgcn_fractf((float)(qs - 1) * xr1);
    const float b1arg = __builtin_amdgcn_fractf((float)qs * xr1);
    f32x2 wa0 = {__builtin_amdgcn_cosf(a0arg), __builtin_amdgcn_sinf(a0arg)};
    f32x2 wb0 = {__builtin_amdgcn_cosf(b0arg), __builtin_amdgcn_sinf(b0arg)};
    f32x2 wa1 = {__builtin_amdgcn_cosf(a1arg), __builtin_amdgcn_sinf(a1arg)};
    f32x2 wb1 = {__builtin_amdgcn_cosf(b1arg), __builtin_amdgcn_sinf(b1arg)};

    f32x2 a00 = {0.f,0.f}, a01 = {0.f,0.f}, a02 = {0.f,0.f}, a03 = {0.f,0.f};
    f32x2 a10 = {0.f,0.f}, a11 = {0.f,0.f}, a12 = {0.f,0.f}, a13 = {0.f,0.f};

    #pragma unroll 2
    for (int g = gbeg; g < gend; ++g) {
        const int q0 = g * 4;
        const float4 h0 = *(const float4*)&hf[0 * RSTRIDE + q0]; // ds_read_b128
        const float4 h1 = *(const float4*)&hf[1 * RSTRIDE + q0];
        const float4 h2 = *(const float4*)&hf[2 * RSTRIDE + q0];
        const float4 h3 = *(const float4*)&hf[3 * RSTRIDE + q0];
        const float r0[4] = {h0.x, h0.y, h0.z, h0.w};
        const float r1[4] = {h1.x, h1.y, h1.z, h1.w};
        const float r2[4] = {h2.x, h2.y, h2.z, h2.w};
        const float r3[4] = {h3.x, h3.y, h3.z, h3.w};
        #pragma unroll
        for (int d = 0; d < 4; ++d) {
            const f32x2 s0 = {r0[d], r0[d]};
            const f32x2 s1 = {r1[d], r1[d]};
            const f32x2 s2 = {r2[d], r2[d]};
            const f32x2 s3 = {r3[d], r3[d]};
            // packed acc: v_pk_fma_f32 (splat h, multiply (cos,sin))
            a00 = __builtin_elementwise_fma(s0, wa0, a00);
            a01 = __builtin_elementwise_fma(s1, wa0, a01);
            a02 = __builtin_elementwise_fma(s2, wa0, a02);
            a03 = __builtin_elementwise_fma(s3, wa0, a03);
            a10 = __builtin_elementwise_fma(s0, wa1, a10);
            a11 = __builtin_elementwise_fma(s1, wa1, a11);
            a12 = __builtin_elementwise_fma(s2, wa1, a12);
            a13 = __builtin_elementwise_fma(s3, wa1, a13);
            // packed Chebyshev step: w_{q+1} = k2*w_q - w_{q-1}
            const f32x2 wn0 = __builtin_elementwise_fma(k20, wb0, -wa0);
            const f32x2 wn1 = __builtin_elementwise_fma(k21, wb1, -wa1);
            wa0 = wb0; wb0 = wn0;
            wa1 = wb1; wb1 = wn1;
        }
    }

    // ---- merge the 4 q-team partials via LDS float atomics, store ----
    float* msumf = (float*)msum;
    {
        const int col0 = c;
        const int col1 = c + 128;
        atomicAdd(&msumf[(0 * K_FIXED + col0) * 2 + 0], a00.x);   // ds_add_f32
        atomicAdd(&msumf[(0 * K_FIXED + col0) * 2 + 1], a00.y);
        atomicAdd(&msumf[(1 * K_FIXED + col0) * 2 + 0], a01.x);
        atomicAdd(&msumf[(1 * K_FIXED + col0) * 2 + 1], a01.y);
        atomicAdd(&msumf[(2 * K_FIXED + col0) * 2 + 0], a02.x);
        atomicAdd(&msumf[(2 * K_FIXED + col0) * 2 + 1], a02.y);
        atomicAdd(&msumf[(3 * K_FIXED + col0) * 2 + 0], a03.x);
        atomicAdd(&msumf[(3 * K_FIXED + col0) * 2 + 1], a03.y);
        atomicAdd(&msumf[(0 * K_FIXED + col1) * 2 + 0], a10.x);
        atomicAdd(&msumf[(0 * K_FIXED + col1) * 2 + 1], a10.y);
        atomicAdd(&msumf[(1 * K_FIXED + col1) * 2 + 0], a11.x);
        atomicAdd(&msumf[(1 * K_FIXED + col1) * 2 + 1], a11.y);
        atomicAdd(&msumf[(2 * K_FIXED + col1) * 2 + 0], a12.x);
        atomicAdd(&msumf[(2 * K_FIXED + col1) * 2 + 1], a12.y);
        atomicAdd(&msumf[(3 * K_FIXED + col1) * 2 + 0], a13.x);
        atomicAdd(&msumf[(3 * K_FIXED + col1) * 2 + 1], a13.y);
    }
    __syncthreads();

    for (int idx = t; idx < ROWS * K_FIXED; idx += NTHREADS) {
        const f32x2 v = msum[idx];
        ((float2*)out)[(size_t)(i0 + (idx >> 8)) * K_FIXED + (idx & 255)] =
            make_float2(v.x, v.y);
    }
}

extern "C" void kernel_launch(void* const* d_in, const int* in_sizes, int n_in,
                              void* d_out, int out_size, void* d_ws, size_t ws_size,
                              hipStream_t stream) {
    const float* coords          = (const float*)d_in[0];
    const unsigned char* mask    = (const unsigned char*)d_in[1];
    const float* wavenumbers     = (const float*)d_in[2];
    float* out                   = (float*)d_out;

    const int K  = in_sizes[2];
    const int BN = in_sizes[0] / 3;        // B*N
    const int N  = N_FIXED;

    if (K != K_FIXED || BN % N != 0 || (N % ROWS) != 0 ||
        (N % NTHREADS) != 0) {
        wf_direct_kernel<<<BN, K, 0, stream>>>(coords, mask, wavenumbers, out, N, K);
        return;
    }

    wf_fused_kernel<<<BN / ROWS, NTHREADS, 0, stream>>>(coords, mask,
                                                        wavenumbers, out, N);
}

// Round 3
// 75.743 us; speedup vs baseline: 1.3924x; 1.3792x over previous
//
#include <hip/hip_runtime.h>
#include <math.h>

// WavefunctionEmbedding, fully fused single kernel (NO workspace):
//   out[b,i,2k+0/1] = sum_j amp_ij * {cos,sin}(wn_k * r_ij)
// Block owns ROWS=4 rows: radial histograms in LDS (cubic Lagrange deposit,
// int32 fixed-point ds_add), then in-block contraction against
// cos/sin(wn_k * r_q) via per-thread Chebyshev recurrence.
//
// R15 = R12 (verified 74.2 us total, ~20 us kernel) with ONE change: the
// contraction team decomposition goes from (q-half x all-4-rows) to
// (row-pair x q-half), thread owns cols c and c+128.
//   - Wave broadcast ds_read_b128: 132 -> 66 per wave (reads = rows_read x
//     groups; splitting ROWS across teams halves rows_read at CPT=2).
//   - Register state is LOWER than R12 (acc 8 + wa/wb 8 + k2 2 + 8 read regs
//     vs R12's 14 + 16 read regs). R13/R14 post-mortem: both regressed to an
//     identical 52.3 us because their contraction state exceeded the
//     allocator's VGPR budget (VGPR_Count 32/48) and spilled to scratch ->
//     latency-bound d-loop (VALUBusy 24%, HBM 1.5%). R15 stays under R12's
//     proven pressure.
//   - Merge reverts to R12's plain-store scheme (qh=1 teams write partials,
//     qh=0 teams add+store). Per-(r,c) accumulation order is IDENTICAL to
//     R12 -> bitwise-same output (absmax 0.03125).
// Deposit phase: byte-identical to R12.

#define N_FIXED  1536
#define K_FIXED  256
#define QBINS    256
#define QG       260            // node q represents r = (q-1)*h
#define ROWS     4              // rows per block (768 blocks = 3/CU)
#define RSTRIDE  272            // hist row stride in floats (16B-aligned)
#define NTHREADS 512
#define FPSCALE  4194304.0f     // 2^22 fixed-point scale for hist deposits

typedef __attribute__((ext_vector_type(2))) float f32x2;

// ---------------- fallback: direct kernel (round-1, known-good) ------------
__global__ __launch_bounds__(256) void wf_direct_kernel(
    const float* __restrict__ coords, const unsigned char* __restrict__ mask,
    const float* __restrict__ wavenumbers, float* __restrict__ out, int N, int K)
{
    __shared__ float2 pairs[N_FIXED];
    const int row = blockIdx.x;
    const int b   = row / N;
    const int i   = row - b * N;
    const int t   = threadIdx.x;
    const float* crow = coords + (size_t)b * N * 3;
    const float xi = crow[i*3+0], yi = crow[i*3+1], zi = crow[i*3+2];
    const unsigned char* mrow = mask + (size_t)b * N;
    for (int j = t; j < N; j += blockDim.x) {
        float dx = crow[j*3+0]-xi, dy = crow[j*3+1]-yi, dz = crow[j*3+2]-zi;
        float d2 = fmaf(dx,dx, fmaf(dy,dy, fmaf(dz,dz, 1e-12f)));
        float r  = sqrtf(d2);
        float amp = 0.07957747154594767f / fmaxf(r, 1e-6f);
        if (j == i || mrow[j]) amp = 0.0f;
        pairs[j] = make_float2(r, amp);
    }
    __syncthreads();
    const int k = t;
    const float f = wavenumbers[k] * 0.15915494309189535f;
    float re = 0.0f, im = 0.0f;
    #pragma unroll 4
    for (int j = 0; j < N; ++j) {
        float2 p = pairs[j];
        float x  = __builtin_amdgcn_fractf(p.x * f);
        float c  = __builtin_amdgcn_cosf(x);
        float s  = __builtin_amdgcn_sinf(x);
        re = fmaf(c, p.y, re);
        im = fmaf(s, p.y, im);
    }
    float2* orow = (float2*)out + (size_t)row * K;
    orow[k] = make_float2(re, im);
}

// ---------------- fused: hist + row-pair/q-half contraction ----------------
__global__ __launch_bounds__(NTHREADS) void wf_fused_kernel(
    const float* __restrict__ coords, const unsigned char* __restrict__ mask,
    const float* __restrict__ wavenumbers, float* __restrict__ out, int N)
{
    __shared__ int   hist[ROWS * RSTRIDE];         // 4.25 KB, r-major
    __shared__ float red[8];
    __shared__ f32x2 merge[ROWS * K_FIXED];        // 8 KB qh=1 partials

    const int i0 = blockIdx.x * ROWS;      // first global row of this block
    const int b  = i0 / N;                 // N % ROWS == 0 -> block within b
    const int t  = threadIdx.x;

    const float* crow = coords + (size_t)b * N * 3;
    const unsigned char* mrow = mask + (size_t)b * N;

    // ---- rmax over THIS BATCH only (h is per-block-consistent) ----
    float m = 0.0f;
    #pragma unroll
    for (int s = 0; s < N_FIXED / NTHREADS; ++s) {
        const int p = t + NTHREADS * s;
        float x = crow[3*p], y = crow[3*p+1], z = crow[3*p+2];
        m = fmaxf(m, fmaf(x,x, fmaf(y,y, z*z)));
    }
    #pragma unroll
    for (int off = 32; off >= 1; off >>= 1)
        m = fmaxf(m, __shfl_down(m, off, 64));
    if ((t & 63) == 0) red[t >> 6] = m;
    for (int a = t; a < ROWS * RSTRIDE; a += NTHREADS) hist[a] = 0;
    __syncthreads();
    float mm = red[0];
    #pragma unroll
    for (int w = 1; w < 8; ++w) mm = fmaxf(mm, red[w]);
    const float rmax = 2.0005f * sqrtf(mm) + 1e-3f;   // r_ij <= 2 max|c|
    const float h    = rmax / (float)QBINS;           // => u = r/h < 256
    const float inv_h = 1.0f / h;

    // ---- histograms: each j loaded once, deposit into all ROWS rows ----
    const int il0 = i0 - b * N;            // local i of row 0
    float cx[ROWS], cy[ROWS], cz[ROWS];
    #pragma unroll
    for (int r = 0; r < ROWS; ++r) {
        cx[r] = crow[3*(il0+r)];
        cy[r] = crow[3*(il0+r)+1];
        cz[r] = crow[3*(il0+r)+2];
    }

    #pragma unroll
    for (int s = 0; s < N_FIXED / NTHREADS; ++s) {
        const int j = t + NTHREADS * s;
        const float xj = crow[3*j], yj = crow[3*j+1], zj = crow[3*j+2];
        const bool masked = (mrow[j] != 0);
        #pragma unroll
        for (int r = 0; r < ROWS; ++r) {
            float dx = xj - cx[r];
            float dy = yj - cy[r];
            float dz = zj - cz[r];
            float d2 = fmaf(dx,dx, fmaf(dy,dy, fmaf(dz,dz, 1e-12f)));
            float rsq = __builtin_amdgcn_rsqf(d2);     // 1/r, r >= 1e-6
            float amp = 0.07957747154594767f * rsq;    // 1/(4 pi r)
            if (j == il0 + r || masked) amp = 0.0f;

            float u  = d2 * rsq * inv_h;               // r/h, in [0,256)
            float qf = floorf(u);
            int   q0 = (int)qf;                        // 0..255, no clamp
            float tt = u - qf;
            // Lagrange cubic through nodes {-1,0,1,2} at offset tt in [0,1)
            float as6 = amp * (FPSCALE * (1.0f/6.0f));
            float as2 = amp * (FPSCALE * 0.5f);
            float tm1 = tt + 1.0f, t1 = tt - 1.0f, t2 = tt - 2.0f;
            float p  = tt  * t1;                       // t(t-1)
            float qq = tm1 * t2;                       // (t+1)(t-2)
            int w0 = (int)(-(p  * t2)  * as6);         // truncating cvt
            int w1 = (int)( (qq * t1)  * as2);
            int w2 = (int)(-(qq * tt)  * as2);
            int w3 = (int)( (p  * tm1) * as6);
            int* hb = &hist[r * RSTRIDE + q0];
            atomicAdd(hb + 0, w0);                     // native ds_add
            atomicAdd(hb + 1, w1);
            atomicAdd(hb + 2, w2);
            atomicAdd(hb + 3, w3);
        }
    }
    __syncthreads();

    // ---- convert int -> float in place (each slot one thread) ----
    float* hf = (float*)hist;
    const float invS = 1.0f / FPSCALE;
    for (int a = t; a < ROWS * RSTRIDE; a += NTHREADS)
        hf[a] = (float)hist[a] * invS;
    __syncthreads();

    // ---- contraction: 4 teams of 128 = (row-pair p, q-half qh);
    //      thread owns cols c and c+128 for rows 2p, 2p+1.
    //      Wave reads 2 rows x ~33 groups = 66 broadcast b128 (was 132). ----
    const int team = t >> 7;               // 0..3
    const int p    = team >> 1;            // row-pair 0 (rows 0,1) / 1 (2,3)
    const int qh   = team & 1;             // q-half
    const int c    = t & 127;              // first owned column
    const int gbeg = qh ? 33 : 0;          // groups of 4 q-nodes
    const int gend = qh ? 65 : 33;         // 65 groups cover q 0..259
    const int qs   = gbeg * 4;

    // theta (revolutions per node) = wn * h / 2pi; per-column Chebyshev
    const float xr0 = wavenumbers[c]       * 0.15915494309189535f * h;
    const float xr1 = wavenumbers[c + 128] * 0.15915494309189535f * h;
    const float k2s0 = 2.0f * __builtin_amdgcn_cosf(__builtin_amdgcn_fractf(xr0));
    const float k2s1 = 2.0f * __builtin_amdgcn_cosf(__builtin_amdgcn_fractf(xr1));
    const f32x2 k20 = {k2s0, k2s0};
    const f32x2 k21 = {k2s1, k2s1};
    // Chebyshev seeds: w_a = cis((qs-1)*th), w_b = cis(qs*th); (cos,sin)
    const float a0arg = __builtin_amdgcn_fractf((float)(qs - 1) * xr0);
    const float b0arg = __builtin_amdgcn_fractf((float)qs * xr0);
    const float a1arg = __builtin_amdgcn_fractf((float)(qs - 1) * xr1);
    const float b1arg = __builtin_amdgcn_fractf((float)qs * xr1);
    f32x2 wa0 = {__builtin_amdgcn_cosf(a0arg), __builtin_amdgcn_sinf(a0arg)};
    f32x2 wb0 = {__builtin_amdgcn_cosf(b0arg), __builtin_amdgcn_sinf(b0arg)};
    f32x2 wa1 = {__builtin_amdgcn_cosf(a1arg), __builtin_amdgcn_sinf(a1arg)};
    f32x2 wb1 = {__builtin_amdgcn_cosf(b1arg), __builtin_amdgcn_sinf(b1arg)};

    // acc[row-in-pair][owned-col]; named scalars only
    f32x2 a00 = {0.f,0.f}, a01 = {0.f,0.f};   // col c  : rows 2p, 2p+1
    f32x2 a10 = {0.f,0.f}, a11 = {0.f,0.f};   // col c+128

    const int r0off = (2*p + 0) * RSTRIDE;
    const int r1off = (2*p + 1) * RSTRIDE;

    #pragma unroll 2
    for (int g = gbeg; g < gend; ++g) {
        const int q0 = g * 4;
        const float4 ha = *(const float4*)&hf[r0off + q0];  // ds_read_b128
        const float4 hb = *(const float4*)&hf[r1off + q0];
        const float ra[4] = {ha.x, ha.y, ha.z, ha.w};
        const float rb[4] = {hb.x, hb.y, hb.z, hb.w};
        #pragma unroll
        for (int d = 0; d < 4; ++d) {
            const f32x2 sa = {ra[d], ra[d]};
            const f32x2 sb = {rb[d], rb[d]};
            // packed acc: v_pk_fma_f32 (splat h, multiply (cos,sin))
            a00 = __builtin_elementwise_fma(sa, wa0, a00);
            a01 = __builtin_elementwise_fma(sb, wa0, a01);
            a10 = __builtin_elementwise_fma(sa, wa1, a10);
            a11 = __builtin_elementwise_fma(sb, wa1, a11);
            // packed Chebyshev step: w_{q+1} = k2*w_q - w_{q-1}
            const f32x2 wn0 = __builtin_elementwise_fma(k20, wb0, -wa0);
            const f32x2 wn1 = __builtin_elementwise_fma(k21, wb1, -wa1);
            wa0 = wb0; wb0 = wn0;
            wa1 = wb1; wb1 = wn1;
        }
    }

    // ---- merge: qh=1 teams store partials, qh=0 teams add + write out ----
    if (qh == 1) {
        merge[(2*p + 0) * K_FIXED + c]       = a00;
        merge[(2*p + 1) * K_FIXED + c]       = a01;
        merge[(2*p + 0) * K_FIXED + c + 128] = a10;
        merge[(2*p + 1) * K_FIXED + c + 128] = a11;
    }
    __syncthreads();
    if (qh == 0) {
        const f32x2 v00 = a00 + merge[(2*p + 0) * K_FIXED + c];
        const f32x2 v01 = a01 + merge[(2*p + 1) * K_FIXED + c];
        const f32x2 v10 = a10 + merge[(2*p + 0) * K_FIXED + c + 128];
        const f32x2 v11 = a11 + merge[(2*p + 1) * K_FIXED + c + 128];
        float2* orow0 = (float2*)out + (size_t)(i0 + 2*p + 0) * K_FIXED;
        float2* orow1 = (float2*)out + (size_t)(i0 + 2*p + 1) * K_FIXED;
        orow0[c]       = make_float2(v00.x, v00.y);
        orow1[c]       = make_float2(v01.x, v01.y);
        orow0[c + 128] = make_float2(v10.x, v10.y);
        orow1[c + 128] = make_float2(v11.x, v11.y);
    }
}

extern "C" void kernel_launch(void* const* d_in, const int* in_sizes, int n_in,
                              void* d_out, int out_size, void* d_ws, size_t ws_size,
                              hipStream_t stream) {
    const float* coords          = (const float*)d_in[0];
    const unsigned char* mask    = (const unsigned char*)d_in[1];
    const float* wavenumbers     = (const float*)d_in[2];
    float* out                   = (float*)d_out;

    const int K  = in_sizes[2];
    const int BN = in_sizes[0] / 3;        // B*N
    const int N  = N_FIXED;

    if (K != K_FIXED || BN % N != 0 || (N % ROWS) != 0 ||
        (N % NTHREADS) != 0) {
        wf_direct_kernel<<<BN, K, 0, stream>>>(coords, mask, wavenumbers, out, N, K);
        return;
    }

    wf_fused_kernel<<<BN / ROWS, NTHREADS, 0, stream>>>(coords, mask,
                                                        wavenumbers, out, N);
}